// Round 4
// baseline (163.996 us; speedup 1.0000x reference)
//
#include <hip/hip_runtime.h>
#include <hip/hip_bf16.h>

typedef short short8 __attribute__((ext_vector_type(8)));
typedef float f32x4 __attribute__((ext_vector_type(4)));

#define N_SPK 1024
#define M_UTT 40
#define D_FEAT 768
#define NROWS (N_SPK * M_UTT)
#define LOG2E 1.44269504088896340736f
#define LN2   0.69314718055994530942f

#define BM 256
#define BN 256
#define BK 64
#define KT (D_FEAT / BK)   // 12 K-tiles
#define ROWB 1536          // bytes per source row (768 * 2)

// ---------------- Kernel 1: fused L2-normalize + inclusive centroid ----------------
// one block per speaker: 40 rows, 2 rows per iteration
__global__ __launch_bounds__(256) void k_norm_cent(const float* __restrict__ x,
                                                   __hip_bfloat16* __restrict__ xn,
                                                   __hip_bfloat16* __restrict__ cc) {
  const int n = blockIdx.x, t = threadIdx.x;
  const float* xb = x + (size_t)n * (M_UTT * D_FEAT);
  __hip_bfloat16* ob = xn + (size_t)n * (M_UTT * D_FEAT);
  const int lane = t & 63, wv = t >> 6;
  __shared__ float wsum[2][2][4];  // [parity][row-in-pair][wave]
  float c0 = 0.f, c1 = 0.f, c2 = 0.f;
  for (int m = 0; m < M_UTT; m += 2) {
    const int p = (m >> 1) & 1;
    const float* r0 = xb + (size_t)m * D_FEAT;
    const float* r1 = r0 + D_FEAT;
    float a0 = r0[t], a1 = r0[t + 256], a2 = r0[t + 512];
    float b0 = r1[t], b1 = r1[t + 256], b2 = r1[t + 512];
    float s0 = a0 * a0 + a1 * a1 + a2 * a2;
    float s1 = b0 * b0 + b1 * b1 + b2 * b2;
#pragma unroll
    for (int d = 1; d < 64; d <<= 1) {
      s0 += __shfl_xor(s0, d, 64);
      s1 += __shfl_xor(s1, d, 64);
    }
    if (lane == 0) { wsum[p][0][wv] = s0; wsum[p][1][wv] = s1; }
    __syncthreads();  // parity double-buffer: reuse of slot p is 2 barriers away -> safe
    const float t0 = wsum[p][0][0] + wsum[p][0][1] + wsum[p][0][2] + wsum[p][0][3];
    const float t1 = wsum[p][1][0] + wsum[p][1][1] + wsum[p][1][2] + wsum[p][1][3];
    const float i0 = 1.0f / fmaxf(sqrtf(t0), 1e-12f);
    const float i1 = 1.0f / fmaxf(sqrtf(t1), 1e-12f);
    a0 *= i0; a1 *= i0; a2 *= i0;
    b0 *= i1; b1 *= i1; b2 *= i1;
    __hip_bfloat16* o0 = ob + (size_t)m * D_FEAT;
    __hip_bfloat16* o1 = o0 + D_FEAT;
    o0[t] = __float2bfloat16(a0); o0[t + 256] = __float2bfloat16(a1); o0[t + 512] = __float2bfloat16(a2);
    o1[t] = __float2bfloat16(b0); o1[t + 256] = __float2bfloat16(b1); o1[t + 512] = __float2bfloat16(b2);
    c0 += a0 + b0; c1 += a1 + b1; c2 += a2 + b2;
  }
  __hip_bfloat16* co = cc + (size_t)n * D_FEAT;
  co[t]       = __float2bfloat16(c0 * (1.0f / M_UTT));
  co[t + 256] = __float2bfloat16(c1 * (1.0f / M_UTT));
  co[t + 512] = __float2bfloat16(c2 * (1.0f / M_UTT));
}

// ---------------- Kernel 2: 256x256 GEMM, 8-phase schedule, fused partial LSE ----------------
// 512 threads = 8 waves (2 row x 4 col); per wave 128x64 output = 8x4 frags of 16x16x32.
// LDS: 2 K-tile buffers x 64KB; buf layout: B0@0 B1@16K A0@32K A1@48K (halves = 128 rows).
// Per K-tile: 4 phases (row-quadrants), staging K-tile k+1 one half-tile per phase in order
// B0,B1,{A0L1,A1L1},{A0L2,A1L2}. Derived waits: next tile's phase0 reads B*+A-L1s -> the 2
// newest loads (A L2s) may stay in flight -> vmcnt(2) at phase3; phase2 reads A-L2s of the
// current tile, guaranteed by vmcnt(4) at phase1 (4 newest = next tile's B loads). Never 0.
#define GLD(g, l) __builtin_amdgcn_global_load_lds( \
    (const __attribute__((address_space(1))) unsigned int*)(g), \
    (__attribute__((address_space(3))) unsigned int*)(l), 16, 0, 0)

#define DS_A(ii, kb) (*(const short8*)(base + aB + (ii) * 2048 + (kb)))
#define DS_B(jj, kb) (*(const short8*)(base + bB + (jj) * 2048 + (kb)))

#define PHASE(Q, STAGE_STMT, WAIT_STMT) do {                                   \
    short8 x00 = DS_A(2 * (Q) + 0, kb0), x01 = DS_A(2 * (Q) + 0, kb1);         \
    short8 x10 = DS_A(2 * (Q) + 1, kb0), x11 = DS_A(2 * (Q) + 1, kb1);         \
    STAGE_STMT;                                                                \
    WAIT_STMT;                                                                 \
    __builtin_amdgcn_s_barrier();                                              \
    asm volatile("s_waitcnt lgkmcnt(0)" ::: "memory");                         \
    __builtin_amdgcn_s_setprio(1);                                             \
    _Pragma("unroll")                                                          \
    for (int j = 0; j < 4; ++j) {                                              \
      acc[2 * (Q) + 0][j] = __builtin_amdgcn_mfma_f32_16x16x32_bf16(x00, bv[j][0], acc[2 * (Q) + 0][j], 0, 0, 0); \
      acc[2 * (Q) + 0][j] = __builtin_amdgcn_mfma_f32_16x16x32_bf16(x01, bv[j][1], acc[2 * (Q) + 0][j], 0, 0, 0); \
      acc[2 * (Q) + 1][j] = __builtin_amdgcn_mfma_f32_16x16x32_bf16(x10, bv[j][0], acc[2 * (Q) + 1][j], 0, 0, 0); \
      acc[2 * (Q) + 1][j] = __builtin_amdgcn_mfma_f32_16x16x32_bf16(x11, bv[j][1], acc[2 * (Q) + 1][j], 0, 0, 0); \
    }                                                                          \
    __builtin_amdgcn_s_setprio(0);                                             \
    __builtin_amdgcn_s_barrier();                                              \
  } while (0)

__global__ __launch_bounds__(512, 2) void k_gemm_part(
    const __hip_bfloat16* __restrict__ XN, const __hip_bfloat16* __restrict__ CC,
    const float* __restrict__ wp, const float* __restrict__ bp,
    float2* __restrict__ ppart, float* __restrict__ picked2) {

  __shared__ __align__(16) char smem[131072];

  const int tid  = threadIdx.x;
  const int wave = tid >> 6, lane = tid & 63;
  const int l16  = lane & 15, lg = lane >> 4;
  const int wr   = wave >> 2, wc = wave & 3;

  // bijective XCD swizzle: 640 blocks = 8 XCD x 80; row-tile's 4 col-blocks contiguous on one XCD
  const int bid = blockIdx.x;
  const int xcd = bid & 7;
  const int idx = bid >> 3;                // 0..79
  const int rb  = xcd * 20 + (idx >> 2);   // 0..159
  const int cb  = idx & 3;                 // 0..3
  const int rowbase = rb * BM;
  const int colbase = cb * BN;

  // staging: thread t covers rows r1 (L1) and r1+64 (L2) of each 128-row half,
  // 16B column slot (tid&7); source column pre-swizzled so LDS is linear-dest swizzled.
  const int r1  = tid >> 3;
  const int fc  = ((tid & 7) * 16) ^ ((r1 & 7) << 4);
  const int t16 = tid * 16;
  const char* pA = (const char*)XN + (size_t)(rowbase + r1) * ROWB + fc;
  const char* pB = (const char*)CC + (size_t)(colbase + r1) * ROWB + fc;

  // ds_read swizzle constants (frag row & 7 == l16 & 7 for all frags)
  const int swz = (l16 & 7) << 4;
  const int kb0 = (lg * 16) ^ swz;
  const int kb1 = (lg * 16 + 64) ^ swz;
  const int aB  = 32768 + wr * 16384 + l16 * 128;
  const int bB  = (wc >> 1) * 16384 + (wc & 1) * 8192 + l16 * 128;

  f32x4 acc[8][4];
#pragma unroll
  for (int i = 0; i < 8; ++i)
#pragma unroll
    for (int j = 0; j < 4; ++j) acc[i][j] = (f32x4){0.f, 0.f, 0.f, 0.f};

  // ---- prologue: stage K-tile 0 into buf0 (canonical order), full drain once ----
  GLD(pB,                 smem + t16);
  GLD(pB +  64 * ROWB,    smem +  8192 + t16);
  GLD(pB + 128 * ROWB,    smem + 16384 + t16);
  GLD(pB + 192 * ROWB,    smem + 24576 + t16);
  GLD(pA,                 smem + 32768 + t16);
  GLD(pA + 128 * ROWB,    smem + 49152 + t16);
  GLD(pA +  64 * ROWB,    smem + 40960 + t16);
  GLD(pA + 192 * ROWB,    smem + 57344 + t16);
  asm volatile("s_waitcnt vmcnt(0)" ::: "memory");
  __builtin_amdgcn_s_barrier();

  short8 bv[4][2];

  for (int k = 0; k < KT; ++k) {
    const char* base = smem + ((k & 1) << 16);
    char* nb = smem + (((k + 1) & 1) << 16);
    const int gk = (k + 1) * (BK * 2);
    const bool st = (k + 1 < KT);

    PHASE(0,
      {
        bv[0][0] = DS_B(0, kb0); bv[0][1] = DS_B(0, kb1);
        bv[1][0] = DS_B(1, kb0); bv[1][1] = DS_B(1, kb1);
        bv[2][0] = DS_B(2, kb0); bv[2][1] = DS_B(2, kb1);
        bv[3][0] = DS_B(3, kb0); bv[3][1] = DS_B(3, kb1);
        if (st) { GLD(pB + gk, nb + t16); GLD(pB + 64 * ROWB + gk, nb + 8192 + t16); }
      }, ;);
    PHASE(1,
      { if (st) { GLD(pB + 128 * ROWB + gk, nb + 16384 + t16); GLD(pB + 192 * ROWB + gk, nb + 24576 + t16); } },
      { if (st) asm volatile("s_waitcnt vmcnt(4)" ::: "memory");
        else    asm volatile("s_waitcnt vmcnt(0)" ::: "memory"); });
    PHASE(2,
      { if (st) { GLD(pA + gk, nb + 32768 + t16); GLD(pA + 128 * ROWB + gk, nb + 49152 + t16); } }, ;);
    PHASE(3,
      { if (st) { GLD(pA + 64 * ROWB + gk, nb + 40960 + t16); GLD(pA + 192 * ROWB + gk, nb + 57344 + t16); } },
      { if (st) asm volatile("s_waitcnt vmcnt(2)" ::: "memory"); });
  }

  // ---- epilogue: diag fixup + per-row (max, sumexp) base-2 partials over 256 cols ----
  const float ws2 = wp[0] * LOG2E;
  const float b2  = bp[0] * LOG2E;
  float2* red = (float2*)smem;  // [256][4] float2 = 8KB, in buf0's B0 area (last reads were buf1)

#pragma unroll
  for (int i = 0; i < 8; ++i) {
#pragma unroll
    for (int rr = 0; rr < 4; ++rr) {
      const int lrow = wr * 128 + i * 16 + lg * 4 + rr;
      const int R = rowbase + lrow;
      const int n = R / M_UTT;
      float l2[4];
#pragma unroll
      for (int j = 0; j < 4; ++j) {
        float sim = acc[i][j][rr];
        const int gc = colbase + wc * 64 + j * 16 + l16;
        if (gc == n) {
          sim = (40.f * sim - 1.f) * (1.f / 39.f);  // exclusive centroid; ||xn|| = 1
          picked2[R] = fmaf(ws2, sim, b2);
        }
        l2[j] = fmaf(ws2, sim, b2);
      }
      float mx = fmaxf(fmaxf(l2[0], l2[1]), fmaxf(l2[2], l2[3]));
#pragma unroll
      for (int d = 1; d < 16; d <<= 1) mx = fmaxf(mx, __shfl_xor(mx, d, 64));
      float s = exp2f(l2[0] - mx) + exp2f(l2[1] - mx) +
                exp2f(l2[2] - mx) + exp2f(l2[3] - mx);
#pragma unroll
      for (int d = 1; d < 16; d <<= 1) s += __shfl_xor(s, d, 64);
      if (l16 == 0) red[lrow * 4 + wc] = make_float2(mx, s);
    }
  }
  __syncthreads();
  if (tid < 256) {
    float2 v0 = red[tid * 4 + 0], v1 = red[tid * 4 + 1];
    float2 v2 = red[tid * 4 + 2], v3 = red[tid * 4 + 3];
    const float m2 = fmaxf(fmaxf(v0.x, v1.x), fmaxf(v2.x, v3.x));
    const float ss = v0.y * exp2f(v0.x - m2) + v1.y * exp2f(v1.x - m2) +
                     v2.y * exp2f(v2.x - m2) + v3.y * exp2f(v3.x - m2);
    ppart[(size_t)(rowbase + tid) * 4 + cb] = make_float2(m2, ss);
  }
}

// ---------------- Kernel 3: combine 4 col-block partials -> row loss ----------------
__global__ __launch_bounds__(256) void k_combine(const float2* __restrict__ pp,
                                                 const float* __restrict__ picked2,
                                                 float* __restrict__ rowloss) {
  const int R = blockIdx.x * 256 + threadIdx.x;
  const float2* p = pp + (size_t)R * 4;
  float2 v[4];
#pragma unroll
  for (int j = 0; j < 4; ++j) v[j] = p[j];
  float m2 = v[0].x;
#pragma unroll
  for (int j = 1; j < 4; ++j) m2 = fmaxf(m2, v[j].x);
  float s = 0.f;
#pragma unroll
  for (int j = 0; j < 4; ++j) s += v[j].y * exp2f(v[j].x - m2);
  const float lse2 = m2 + log2f(s);
  rowloss[R] = (lse2 - picked2[R]) * LN2;
}

// ---------------- Kernel 4: mean over all 40960 rows ----------------
__global__ __launch_bounds__(512) void k_reduce(const float* __restrict__ rowloss,
                                                float* __restrict__ out) {
  const int t = threadIdx.x;
  double s = 0.0;
  for (int i = t; i < NROWS; i += 512) s += (double)rowloss[i];
  __shared__ double sm[512];
  sm[t] = s;
  __syncthreads();
  for (int off = 256; off > 0; off >>= 1) {
    if (t < off) sm[t] += sm[t + off];
    __syncthreads();
  }
  if (t == 0) out[0] = (float)(sm[0] / (double)NROWS);
}

extern "C" void kernel_launch(void* const* d_in, const int* in_sizes, int n_in,
                              void* d_out, int out_size, void* d_ws, size_t ws_size,
                              hipStream_t stream) {
  const float* x = (const float*)d_in[0];
  const float* w = (const float*)d_in[1];
  const float* b = (const float*)d_in[2];
  char* ws = (char*)d_ws;
  size_t off = 0;
  __hip_bfloat16* xn = (__hip_bfloat16*)(ws + off); off += (size_t)NROWS * D_FEAT * 2;
  __hip_bfloat16* cc = (__hip_bfloat16*)(ws + off); off += (size_t)N_SPK * D_FEAT * 2;
  float2* ppart      = (float2*)(ws + off);         off += (size_t)NROWS * 4 * sizeof(float2);
  float* picked2     = (float*)(ws + off);          off += (size_t)NROWS * sizeof(float);
  float* rowloss     = (float*)(ws + off);          off += (size_t)NROWS * sizeof(float);
  float* out = (float*)d_out;

  k_norm_cent<<<N_SPK, 256, 0, stream>>>(x, xn, cc);
  k_gemm_part<<<(NROWS / BM) * (N_SPK / BN), 512, 0, stream>>>(xn, cc, w, b, ppart, picked2);
  k_combine<<<NROWS / 256, 256, 0, stream>>>(ppart, picked2, rowloss);
  k_reduce<<<1, 512, 0, stream>>>(rowloss, out);
}

// Round 5
// 162.346 us; speedup vs baseline: 1.0102x; 1.0102x over previous
//
#include <hip/hip_runtime.h>
#include <hip/hip_bf16.h>

typedef short short8 __attribute__((ext_vector_type(8)));
typedef float f32x4 __attribute__((ext_vector_type(4)));

#define N_SPK 1024
#define M_UTT 40
#define D_FEAT 768
#define NROWS (N_SPK * M_UTT)
#define LOG2E 1.44269504088896340736f
#define LN2   0.69314718055994530942f

#define BM 256
#define BN 128
#define BK 64
#define KT (D_FEAT / BK)   // 12 K-tiles
#define ROWB 1536          // bytes per source row (768 * 2)

// ---------------- Kernel 1: fused L2-normalize + inclusive centroid ----------------
__global__ __launch_bounds__(256) void k_norm_cent(const float* __restrict__ x,
                                                   __hip_bfloat16* __restrict__ xn,
                                                   __hip_bfloat16* __restrict__ cc) {
  const int n = blockIdx.x, t = threadIdx.x;
  const float* xb = x + (size_t)n * (M_UTT * D_FEAT);
  __hip_bfloat16* ob = xn + (size_t)n * (M_UTT * D_FEAT);
  const int lane = t & 63, wv = t >> 6;
  __shared__ float wsum[2][2][4];  // [parity][row-in-pair][wave]
  float c0 = 0.f, c1 = 0.f, c2 = 0.f;
  for (int m = 0; m < M_UTT; m += 2) {
    const int p = (m >> 1) & 1;
    const float* r0 = xb + (size_t)m * D_FEAT;
    const float* r1 = r0 + D_FEAT;
    float a0 = r0[t], a1 = r0[t + 256], a2 = r0[t + 512];
    float b0 = r1[t], b1 = r1[t + 256], b2 = r1[t + 512];
    float s0 = a0 * a0 + a1 * a1 + a2 * a2;
    float s1 = b0 * b0 + b1 * b1 + b2 * b2;
#pragma unroll
    for (int d = 1; d < 64; d <<= 1) {
      s0 += __shfl_xor(s0, d, 64);
      s1 += __shfl_xor(s1, d, 64);
    }
    if (lane == 0) { wsum[p][0][wv] = s0; wsum[p][1][wv] = s1; }
    __syncthreads();  // parity double-buffer: slot p reused 2 barriers later -> safe
    const float t0 = wsum[p][0][0] + wsum[p][0][1] + wsum[p][0][2] + wsum[p][0][3];
    const float t1 = wsum[p][1][0] + wsum[p][1][1] + wsum[p][1][2] + wsum[p][1][3];
    const float i0 = 1.0f / fmaxf(sqrtf(t0), 1e-12f);
    const float i1 = 1.0f / fmaxf(sqrtf(t1), 1e-12f);
    a0 *= i0; a1 *= i0; a2 *= i0;
    b0 *= i1; b1 *= i1; b2 *= i1;
    __hip_bfloat16* o0 = ob + (size_t)m * D_FEAT;
    __hip_bfloat16* o1 = o0 + D_FEAT;
    o0[t] = __float2bfloat16(a0); o0[t + 256] = __float2bfloat16(a1); o0[t + 512] = __float2bfloat16(a2);
    o1[t] = __float2bfloat16(b0); o1[t + 256] = __float2bfloat16(b1); o1[t + 512] = __float2bfloat16(b2);
    c0 += a0 + b0; c1 += a1 + b1; c2 += a2 + b2;
  }
  __hip_bfloat16* co = cc + (size_t)n * D_FEAT;
  co[t]       = __float2bfloat16(c0 * (1.0f / M_UTT));
  co[t + 256] = __float2bfloat16(c1 * (1.0f / M_UTT));
  co[t + 512] = __float2bfloat16(c2 * (1.0f / M_UTT));
}

// ---------------- Kernel 2: 256x128 GEMM tiles, 2 blocks/CU, fused partial LSE ----------------
// 256 threads = 4 waves (2 row-bands x 2 col-halves); wave = 128x64 out = 8x4 frags,
// 64 MFMA per K-tile. Single 48KB LDS buffer (A 32KB + B 16KB), XOR-swizzled rows;
// serial {stage -> drain -> compute} per tile; the co-resident block provides the
// overlap (m97/m114 implicit wave-level pipelining at 2 blocks/CU).
#define GLD(g, l) __builtin_amdgcn_global_load_lds( \
    (const __attribute__((address_space(1))) unsigned int*)(g), \
    (__attribute__((address_space(3))) unsigned int*)(l), 16, 0, 0)

__global__ __launch_bounds__(256, 2) void k_gemm_part(
    const __hip_bfloat16* __restrict__ XN, const __hip_bfloat16* __restrict__ CC,
    const float* __restrict__ wp, const float* __restrict__ bp,
    float2* __restrict__ ppart, float* __restrict__ picked2) {

  __shared__ __align__(16) char smem[49152];

  const int tid  = threadIdx.x;
  const int wave = tid >> 6, lane = tid & 63;
  const int l16  = lane & 15, lg = lane >> 4;
  const int wr   = wave >> 1, wc = wave & 1;

  // bijective XCD swizzle: 1280 = 8 XCD x 160; a row-tile's 8 col-blocks stay on one XCD
  const int bid = blockIdx.x;
  const int xcd = bid & 7;
  const int idx = bid >> 3;                // 0..159
  const int rb  = xcd * 20 + (idx >> 3);   // 0..159
  const int cb  = idx & 7;                 // 0..7
  const int rowbase = rb * BM;
  const int colbase = cb * BN;

  // staging: thread t -> row r0 = tid>>3 (+32 per GLD step), 16B slot tid&7;
  // global column pre-swizzled so linear LDS dest holds the swizzled layout.
  const int r0  = tid >> 3;
  const int fc  = ((tid & 7) * 16) ^ ((r0 & 7) << 4);
  const int t16 = tid * 16;
  const char* gA = (const char*)XN + (size_t)(rowbase + r0) * ROWB + fc;
  const char* gB = (const char*)CC + (size_t)(colbase + r0) * ROWB + fc;

  // ds_read constants: row byte = row*128, in-row offset (lg*16 [+64]) ^ ((row&7)<<4)
  const int swz = (l16 & 7) << 4;
  const int kb0 = (lg * 16) ^ swz;
  const int kb1 = (lg * 16 + 64) ^ swz;
  const int aBase = wr * 16384 + l16 * 128;          // A @0: rows wr*128 + ii*16 + l16
  const int bBase = 32768 + wc * 8192 + l16 * 128;   // B @32K: cols wc*64 + j*16 + l16

  f32x4 acc[8][4];
#pragma unroll
  for (int i = 0; i < 8; ++i)
#pragma unroll
    for (int j = 0; j < 4; ++j) acc[i][j] = (f32x4){0.f, 0.f, 0.f, 0.f};

  for (int k = 0; k < KT; ++k) {
    // ---- stage tile k (A: 8 GLD covering 256 rows, B: 4 GLD covering 128 rows) ----
#pragma unroll
    for (int q = 0; q < 8; ++q) GLD(gA + (size_t)q * (32 * ROWB), smem + q * 4096 + t16);
#pragma unroll
    for (int q = 0; q < 4; ++q) GLD(gB + (size_t)q * (32 * ROWB), smem + 32768 + q * 4096 + t16);
    gA += BK * 2;
    gB += BK * 2;
    asm volatile("s_waitcnt vmcnt(0)" ::: "memory");
    __builtin_amdgcn_s_barrier();

    // ---- compute: 2 k-substeps x (8 A-frags, 4 B-frags, 32 MFMA) ----
#pragma unroll
    for (int s = 0; s < 2; ++s) {
      const int kb = s ? kb1 : kb0;
      short8 av[8], bv[4];
#pragma unroll
      for (int i = 0; i < 8; ++i) av[i] = *(const short8*)(smem + aBase + i * 2048 + kb);
#pragma unroll
      for (int j = 0; j < 4; ++j) bv[j] = *(const short8*)(smem + bBase + j * 2048 + kb);
      __builtin_amdgcn_s_setprio(1);
#pragma unroll
      for (int i = 0; i < 8; ++i)
#pragma unroll
        for (int j = 0; j < 4; ++j)
          acc[i][j] = __builtin_amdgcn_mfma_f32_16x16x32_bf16(av[i], bv[j], acc[i][j], 0, 0, 0);
      __builtin_amdgcn_s_setprio(0);
    }
    __builtin_amdgcn_s_barrier();  // all reads done before next stage overwrites
  }

  // ---- epilogue: diag fixup + per-row (max, sumexp) base-2 partials over 128 cols ----
  const float ws2 = wp[0] * LOG2E;
  const float b2  = bp[0] * LOG2E;
  float2* red = (float2*)smem;  // [256][2] float2 = 4KB, safe after final barrier

#pragma unroll
  for (int i = 0; i < 8; ++i) {
#pragma unroll
    for (int rr = 0; rr < 4; ++rr) {
      const int lrow = wr * 128 + i * 16 + lg * 4 + rr;   // 0..255
      const int R = rowbase + lrow;
      const int n = R / M_UTT;
      float l2[4];
#pragma unroll
      for (int j = 0; j < 4; ++j) {
        float sim = acc[i][j][rr];
        const int gc = colbase + wc * 64 + j * 16 + l16;
        if (gc == n) {
          sim = (40.f * sim - 1.f) * (1.f / 39.f);  // exclusive centroid; ||xn|| = 1
          picked2[R] = fmaf(ws2, sim, b2);
        }
        l2[j] = fmaf(ws2, sim, b2);
      }
      float mx = fmaxf(fmaxf(l2[0], l2[1]), fmaxf(l2[2], l2[3]));
#pragma unroll
      for (int d = 1; d < 16; d <<= 1) mx = fmaxf(mx, __shfl_xor(mx, d, 64));
      float s = exp2f(l2[0] - mx) + exp2f(l2[1] - mx) +
                exp2f(l2[2] - mx) + exp2f(l2[3] - mx);
#pragma unroll
      for (int d = 1; d < 16; d <<= 1) s += __shfl_xor(s, d, 64);
      if (l16 == 0) red[lrow * 2 + wc] = make_float2(mx, s);
    }
  }
  __syncthreads();
  // combine the two col-half partials -> one partial per row for this col-block
  {
    const float2 p0 = red[tid * 2 + 0];
    const float2 p1 = red[tid * 2 + 1];
    const float m2 = fmaxf(p0.x, p1.x);
    const float ss = p0.y * exp2f(p0.x - m2) + p1.y * exp2f(p1.x - m2);
    ppart[(size_t)(rowbase + tid) * 8 + cb] = make_float2(m2, ss);
  }
}

// ---------------- Kernel 3: combine 8 col-block partials -> row loss ----------------
__global__ __launch_bounds__(256) void k_combine(const float2* __restrict__ pp,
                                                 const float* __restrict__ picked2,
                                                 float* __restrict__ rowloss) {
  const int R = blockIdx.x * 256 + threadIdx.x;
  const float2* p = pp + (size_t)R * 8;
  float2 v[8];
#pragma unroll
  for (int j = 0; j < 8; ++j) v[j] = p[j];
  float m2 = v[0].x;
#pragma unroll
  for (int j = 1; j < 8; ++j) m2 = fmaxf(m2, v[j].x);
  float s = 0.f;
#pragma unroll
  for (int j = 0; j < 8; ++j) s += v[j].y * exp2f(v[j].x - m2);
  const float lse2 = m2 + log2f(s);
  rowloss[R] = (lse2 - picked2[R]) * LN2;
}

// ---------------- Kernel 4: mean over all 40960 rows ----------------
__global__ __launch_bounds__(512) void k_reduce(const float* __restrict__ rowloss,
                                                float* __restrict__ out) {
  const int t = threadIdx.x;
  double s = 0.0;
  for (int i = t; i < NROWS; i += 512) s += (double)rowloss[i];
  __shared__ double sm[512];
  sm[t] = s;
  __syncthreads();
  for (int off = 256; off > 0; off >>= 1) {
    if (t < off) sm[t] += sm[t + off];
    __syncthreads();
  }
  if (t == 0) out[0] = (float)(sm[0] / (double)NROWS);
}

extern "C" void kernel_launch(void* const* d_in, const int* in_sizes, int n_in,
                              void* d_out, int out_size, void* d_ws, size_t ws_size,
                              hipStream_t stream) {
  const float* x = (const float*)d_in[0];
  const float* w = (const float*)d_in[1];
  const float* b = (const float*)d_in[2];
  char* ws = (char*)d_ws;
  size_t off = 0;
  __hip_bfloat16* xn = (__hip_bfloat16*)(ws + off); off += (size_t)NROWS * D_FEAT * 2;
  __hip_bfloat16* cc = (__hip_bfloat16*)(ws + off); off += (size_t)N_SPK * D_FEAT * 2;
  float2* ppart      = (float2*)(ws + off);         off += (size_t)NROWS * 8 * sizeof(float2);
  float* picked2     = (float*)(ws + off);          off += (size_t)NROWS * sizeof(float);
  float* rowloss     = (float*)(ws + off);          off += (size_t)NROWS * sizeof(float);
  float* out = (float*)d_out;

  k_norm_cent<<<N_SPK, 256, 0, stream>>>(x, xn, cc);
  k_gemm_part<<<(NROWS / BM) * (N_SPK / BN), 256, 0, stream>>>(xn, cc, w, b, ppart, picked2);
  k_combine<<<NROWS / 256, 256, 0, stream>>>(ppart, picked2, rowloss);
  k_reduce<<<1, 512, 0, stream>>>(rowloss, out);
}

// Round 6
// 142.150 us; speedup vs baseline: 1.1537x; 1.1421x over previous
//
#include <hip/hip_runtime.h>
#include <hip/hip_bf16.h>

typedef short short8 __attribute__((ext_vector_type(8)));
typedef float f32x4 __attribute__((ext_vector_type(4)));

#define N_SPK 1024
#define M_UTT 40
#define D_FEAT 768
#define NROWS (N_SPK * M_UTT)
#define LOG2E 1.44269504088896340736f
#define LN2   0.69314718055994530942f

#define BM 128
#define BN 128
#define BK 32
#define KT (D_FEAT / BK)   // 24 K-tiles
#define ROWB 1536          // bytes per source row (768 * 2)

// ---------------- Kernel 1: fused L2-normalize + inclusive centroid ----------------
__global__ __launch_bounds__(256) void k_norm_cent(const float* __restrict__ x,
                                                   __hip_bfloat16* __restrict__ xn,
                                                   __hip_bfloat16* __restrict__ cc) {
  const int n = blockIdx.x, t = threadIdx.x;
  const float* xb = x + (size_t)n * (M_UTT * D_FEAT);
  __hip_bfloat16* ob = xn + (size_t)n * (M_UTT * D_FEAT);
  const int lane = t & 63, wv = t >> 6;
  __shared__ float wsum[2][2][4];  // [parity][row-in-pair][wave]
  float c0 = 0.f, c1 = 0.f, c2 = 0.f;
  for (int m = 0; m < M_UTT; m += 2) {
    const int p = (m >> 1) & 1;
    const float* r0 = xb + (size_t)m * D_FEAT;
    const float* r1 = r0 + D_FEAT;
    float a0 = r0[t], a1 = r0[t + 256], a2 = r0[t + 512];
    float b0 = r1[t], b1 = r1[t + 256], b2 = r1[t + 512];
    float s0 = a0 * a0 + a1 * a1 + a2 * a2;
    float s1 = b0 * b0 + b1 * b1 + b2 * b2;
#pragma unroll
    for (int d = 1; d < 64; d <<= 1) {
      s0 += __shfl_xor(s0, d, 64);
      s1 += __shfl_xor(s1, d, 64);
    }
    if (lane == 0) { wsum[p][0][wv] = s0; wsum[p][1][wv] = s1; }
    __syncthreads();  // parity double-buffer: slot p reused 2 barriers later -> safe
    const float t0 = wsum[p][0][0] + wsum[p][0][1] + wsum[p][0][2] + wsum[p][0][3];
    const float t1 = wsum[p][1][0] + wsum[p][1][1] + wsum[p][1][2] + wsum[p][1][3];
    const float i0 = 1.0f / fmaxf(sqrtf(t0), 1e-12f);
    const float i1 = 1.0f / fmaxf(sqrtf(t1), 1e-12f);
    a0 *= i0; a1 *= i0; a2 *= i0;
    b0 *= i1; b1 *= i1; b2 *= i1;
    __hip_bfloat16* o0 = ob + (size_t)m * D_FEAT;
    __hip_bfloat16* o1 = o0 + D_FEAT;
    o0[t] = __float2bfloat16(a0); o0[t + 256] = __float2bfloat16(a1); o0[t + 512] = __float2bfloat16(a2);
    o1[t] = __float2bfloat16(b0); o1[t + 256] = __float2bfloat16(b1); o1[t + 512] = __float2bfloat16(b2);
    c0 += a0 + b0; c1 += a1 + b1; c2 += a2 + b2;
  }
  __hip_bfloat16* co = cc + (size_t)n * D_FEAT;
  co[t]       = __float2bfloat16(c0 * (1.0f / M_UTT));
  co[t + 256] = __float2bfloat16(c1 * (1.0f / M_UTT));
  co[t + 512] = __float2bfloat16(c2 * (1.0f / M_UTT));
}

// ---------------- Kernel 2: 128x128 GEMM, BK=32, 3 blocks/CU, counted vmcnt ----------------
// 256 thr = 4 waves (2x2 of 64x64, 4x4 frags each, 16 MFMA per K-tile).
// LDS 32KB: dbuf x 16KB; each src 64B row pair-packed into 128B LDS rows with
// 3-bit XOR swizzle (physical_inner = logical_inner ^ ((R&7)<<4); bit6 = row parity).
// Loop: stage k+1 -> vmcnt(4) (tile-k's loads done, k+1's stay in flight across the
// barrier) -> barrier -> ds_read+MFMA -> lgkmcnt(0) -> barrier. Never vmcnt(0) mid-loop.
#define GLD(g, l) __builtin_amdgcn_global_load_lds( \
    (const __attribute__((address_space(1))) unsigned int*)(g), \
    (__attribute__((address_space(3))) unsigned int*)(l), 16, 0, 0)

__global__ __launch_bounds__(256, 3) void k_gemm_part(
    const __hip_bfloat16* __restrict__ XN, const __hip_bfloat16* __restrict__ CC,
    const float* __restrict__ wp, const float* __restrict__ bp,
    float2* __restrict__ ppart, float* __restrict__ picked2) {

  __shared__ __align__(16) char smem[32768];

  const int tid  = threadIdx.x;
  const int wave = tid >> 6, lane = tid & 63;
  const int l16  = lane & 15, lg = lane >> 4;
  const int wr   = wave >> 1, wc = wave & 1;

  // XCD swizzle: 2560 = 8 XCD x 320; the 8 col-blocks of a row-tile share one XCD's L2
  const int bid = blockIdx.x;
  const int xcd = bid & 7;
  const int tt  = bid >> 3;              // 0..319
  const int rb  = xcd * 40 + (tt >> 3);  // 0..319
  const int cb  = tt & 7;                // 0..7
  const int rowbase = rb * BM;
  const int colbase = cb * BN;

  // staging source mapping (inverse of the pair-packed swizzle):
  // thread t fills LDS linear bytes o = chunk*4096 + t*16; LDS-row R = o>>7,
  // logical_inner = (o&127) ^ ((R&7)<<4); src_row = 2R + (logical_inner>>6),
  // src k-byte = logical_inner & 63.
  const int R7   = (tid >> 3) & 7;
  const int li   = ((tid & 7) * 16) ^ (R7 << 4);
  const int row0 = 2 * (tid >> 3) + (li >> 6);   // 0..63
  const int kb   = li & 63;
  const int t16  = tid * 16;
  const char* gA = (const char*)XN + (size_t)(rowbase + row0) * ROWB + kb;
  const char* gB = (const char*)CC + (size_t)(colbase + row0) * ROWB + kb;

  // fragment ds_read offsets: src row r = band*64 + i*16 + l16 ->
  // LDS-row R = band*32 + i*8 + (l16>>1); inner = (((l16&1)<<6)|(lg<<4)) ^ ((R&7)<<4)
  const int xr  = ((l16 >> 1) & 7) << 4;
  const int inr = ((((l16 & 1) << 6) | (lg << 4)) ^ xr);
  int aoff[4], boff[4];
#pragma unroll
  for (int i = 0; i < 4; ++i) {
    aoff[i] = (wr * 32 + i * 8 + (l16 >> 1)) * 128 + inr;
    boff[i] = 8192 + (wc * 32 + i * 8 + (l16 >> 1)) * 128 + inr;
  }

  f32x4 acc[4][4];
#pragma unroll
  for (int i = 0; i < 4; ++i)
#pragma unroll
    for (int j = 0; j < 4; ++j) acc[i][j] = (f32x4){0.f, 0.f, 0.f, 0.f};

  auto STAGE = [&](int buf, int koff) {
    char* sb = smem + buf * 16384;
    GLD(gA + koff,             sb + t16);
    GLD(gA + 64 * ROWB + koff, sb + 4096 + t16);
    GLD(gB + koff,             sb + 8192 + t16);
    GLD(gB + 64 * ROWB + koff, sb + 12288 + t16);
  };

  STAGE(0, 0);  // prologue: tile 0

  for (int k = 0; k < KT; ++k) {
    const char* bb = smem + (k & 1) * 16384;
    if (k + 1 < KT) {
      STAGE((k + 1) & 1, (k + 1) * (BK * 2));
      asm volatile("s_waitcnt vmcnt(4)" ::: "memory");  // tile k landed; k+1 in flight
    } else {
      asm volatile("s_waitcnt vmcnt(0)" ::: "memory");
    }
    __builtin_amdgcn_s_barrier();

    short8 av[4], bv[4];
#pragma unroll
    for (int i = 0; i < 4; ++i) av[i] = *(const short8*)(bb + aoff[i]);
#pragma unroll
    for (int j = 0; j < 4; ++j) bv[j] = *(const short8*)(bb + boff[j]);
    __builtin_amdgcn_s_setprio(1);
#pragma unroll
    for (int i = 0; i < 4; ++i)
#pragma unroll
      for (int j = 0; j < 4; ++j)
        acc[i][j] = __builtin_amdgcn_mfma_f32_16x16x32_bf16(av[i], bv[j], acc[i][j], 0, 0, 0);
    __builtin_amdgcn_s_setprio(0);
    asm volatile("s_waitcnt lgkmcnt(0)" ::: "memory");  // reads complete before overwrite
    __builtin_amdgcn_s_barrier();
  }

  // ---- epilogue: diag fixup + per-row (max, sumexp) base-2 partials over 128 cols ----
  const float ws2 = wp[0] * LOG2E;
  const float b2  = bp[0] * LOG2E;
  float2* red = (float2*)smem;  // [128][2] float2 = 2KB, safe after final barrier

#pragma unroll
  for (int i = 0; i < 4; ++i) {
#pragma unroll
    for (int rr = 0; rr < 4; ++rr) {
      const int lrow = wr * 64 + i * 16 + lg * 4 + rr;  // 0..127
      const int R = rowbase + lrow;
      const int n = R / M_UTT;
      float l2[4];
#pragma unroll
      for (int j = 0; j < 4; ++j) {
        float sim = acc[i][j][rr];
        const int gc = colbase + wc * 64 + j * 16 + l16;
        if (gc == n) {
          sim = (40.f * sim - 1.f) * (1.f / 39.f);  // exclusive centroid; ||xn|| = 1
          picked2[R] = fmaf(ws2, sim, b2);
        }
        l2[j] = fmaf(ws2, sim, b2);
      }
      float mx = fmaxf(fmaxf(l2[0], l2[1]), fmaxf(l2[2], l2[3]));
#pragma unroll
      for (int d = 1; d < 16; d <<= 1) mx = fmaxf(mx, __shfl_xor(mx, d, 64));
      float s = exp2f(l2[0] - mx) + exp2f(l2[1] - mx) +
                exp2f(l2[2] - mx) + exp2f(l2[3] - mx);
#pragma unroll
      for (int d = 1; d < 16; d <<= 1) s += __shfl_xor(s, d, 64);
      if (l16 == 0) red[lrow * 2 + wc] = make_float2(mx, s);
    }
  }
  __syncthreads();
  if (tid < 128) {
    const float2 p0 = red[tid * 2 + 0];
    const float2 p1 = red[tid * 2 + 1];
    const float m2 = fmaxf(p0.x, p1.x);
    const float ss = p0.y * exp2f(p0.x - m2) + p1.y * exp2f(p1.x - m2);
    ppart[(size_t)(rowbase + tid) * 8 + cb] = make_float2(m2, ss);
  }
}

// ---------------- Kernel 3: combine 8 col-block partials -> row loss ----------------
__global__ __launch_bounds__(256) void k_combine(const float2* __restrict__ pp,
                                                 const float* __restrict__ picked2,
                                                 float* __restrict__ rowloss) {
  const int R = blockIdx.x * 256 + threadIdx.x;
  const float2* p = pp + (size_t)R * 8;
  float2 v[8];
#pragma unroll
  for (int j = 0; j < 8; ++j) v[j] = p[j];
  float m2 = v[0].x;
#pragma unroll
  for (int j = 1; j < 8; ++j) m2 = fmaxf(m2, v[j].x);
  float s = 0.f;
#pragma unroll
  for (int j = 0; j < 8; ++j) s += v[j].y * exp2f(v[j].x - m2);
  const float lse2 = m2 + log2f(s);
  rowloss[R] = (lse2 - picked2[R]) * LN2;
}

// ---------------- Kernel 4: mean over all 40960 rows ----------------
__global__ __launch_bounds__(512) void k_reduce(const float* __restrict__ rowloss,
                                                float* __restrict__ out) {
  const int t = threadIdx.x;
  double s = 0.0;
  for (int i = t; i < NROWS; i += 512) s += (double)rowloss[i];
  __shared__ double sm[512];
  sm[t] = s;
  __syncthreads();
  for (int off = 256; off > 0; off >>= 1) {
    if (t < off) sm[t] += sm[t + off];
    __syncthreads();
  }
  if (t == 0) out[0] = (float)(sm[0] / (double)NROWS);
}

extern "C" void kernel_launch(void* const* d_in, const int* in_sizes, int n_in,
                              void* d_out, int out_size, void* d_ws, size_t ws_size,
                              hipStream_t stream) {
  const float* x = (const float*)d_in[0];
  const float* w = (const float*)d_in[1];
  const float* b = (const float*)d_in[2];
  char* ws = (char*)d_ws;
  size_t off = 0;
  __hip_bfloat16* xn = (__hip_bfloat16*)(ws + off); off += (size_t)NROWS * D_FEAT * 2;
  __hip_bfloat16* cc = (__hip_bfloat16*)(ws + off); off += (size_t)N_SPK * D_FEAT * 2;
  float2* ppart      = (float2*)(ws + off);         off += (size_t)NROWS * 8 * sizeof(float2);
  float* picked2     = (float*)(ws + off);          off += (size_t)NROWS * sizeof(float);
  float* rowloss     = (float*)(ws + off);          off += (size_t)NROWS * sizeof(float);
  float* out = (float*)d_out;

  k_norm_cent<<<N_SPK, 256, 0, stream>>>(x, xn, cc);
  k_gemm_part<<<(NROWS / BM) * (N_SPK / BN), 256, 0, stream>>>(xn, cc, w, b, ppart, picked2);
  k_combine<<<NROWS / 256, 256, 0, stream>>>(ppart, picked2, rowloss);
  k_reduce<<<1, 512, 0, stream>>>(rowloss, out);
}